// Round 1
// baseline (32.954 us; speedup 1.0000x reference)
//
#include <hip/hip_runtime.h>

// out[b, m] = sum_n exp(-0.5 * ||inputs[b,n] - stars[m]||^2)
// B=32, N=4096, M=1024, D=3, fp32 in/out.
//
// Rewrite: exp(-0.5*d2) = 2^(-c2*d2), c2 = 0.5*log2(e)
//   -c2*d2 = q + (L2E*sx)*x + (L2E*sy)*y + (L2E*sz)*z + (-c2*||s||^2)
//   with q = -c2*||x||^2 precomputed per point as E = 2^q.
// Inner loop per (point, star): 3 fma + 1 v_exp_f32 + 1 fma.

#define NB 32
#define NN 4096
#define NM 1024
#define NCHUNK 32               // blocks per batch along N
#define NPB (NN / NCHUNK)       // 128 points per block
#define TPB 128                 // threads per block (2 waves)
#define MPT (NM / TPB)          // 8 stars per thread

__device__ __forceinline__ float exp2_hw(float x) {
#if __has_builtin(__builtin_amdgcn_exp2f)
    return __builtin_amdgcn_exp2f(x);
#else
    float r;
    asm("v_exp_f32 %0, %1" : "=v"(r) : "v"(x));
    return r;
#endif
}

__global__ __launch_bounds__(256) void gau_zero(float* __restrict__ out) {
    out[blockIdx.x * 256 + threadIdx.x] = 0.0f;
}

__global__ __launch_bounds__(TPB) void gau_main(const float* __restrict__ inputs,
                                                const float* __restrict__ stars,
                                                float* __restrict__ out) {
    constexpr float C2  = 0.72134752044448169f;  // 0.5*log2(e)
    constexpr float L2E = 1.44269504088896340f;  // log2(e)

    const int b     = blockIdx.x / NCHUNK;
    const int chunk = blockIdx.x % NCHUNK;
    const int t     = threadIdx.x;

    __shared__ float4 pts[NPB];  // (x, y, z, E=2^(-C2*||x||^2))

    // Stage this block's 128 points into LDS, precomputing E.
    {
        const float* p = inputs + ((size_t)b * NN + (size_t)chunk * NPB + t) * 3;
        float x = p[0], y = p[1], z = p[2];
        float q = -C2 * x * x - C2 * y * y - C2 * z * z;
        pts[t] = make_float4(x, y, z, exp2_hw(q));
    }

    // Per-thread star constants: m = t + k*TPB, k = 0..7
    float Sx[MPT], Sy[MPT], Sz[MPT], K[MPT];
#pragma unroll
    for (int k = 0; k < MPT; ++k) {
        int m = t + k * TPB;
        float sx = stars[3 * m + 0];
        float sy = stars[3 * m + 1];
        float sz = stars[3 * m + 2];
        Sx[k] = L2E * sx;
        Sy[k] = L2E * sy;
        Sz[k] = L2E * sz;
        K[k]  = -C2 * (sx * sx + sy * sy + sz * sz);
    }

    float acc[MPT];
#pragma unroll
    for (int k = 0; k < MPT; ++k) acc[k] = 0.0f;

    __syncthreads();

#pragma unroll 4
    for (int i = 0; i < NPB; ++i) {
        float4 p = pts[i];  // uniform address -> LDS broadcast, conflict-free
#pragma unroll
        for (int k = 0; k < MPT; ++k) {
            float inner = fmaf(Sx[k], p.x, fmaf(Sy[k], p.y, fmaf(Sz[k], p.z, K[k])));
            float e = exp2_hw(inner);
            acc[k] = fmaf(p.w, e, acc[k]);
        }
    }

    float* ob = out + (size_t)b * NM;
#pragma unroll
    for (int k = 0; k < MPT; ++k) {
        atomicAdd(ob + t + k * TPB, acc[k]);
    }
}

extern "C" void kernel_launch(void* const* d_in, const int* in_sizes, int n_in,
                              void* d_out, int out_size, void* d_ws, size_t ws_size,
                              hipStream_t stream) {
    const float* inputs = (const float*)d_in[0];  // (32, 4096, 3)
    const float* stars  = (const float*)d_in[1];  // (1024, 3)
    float* out = (float*)d_out;                   // (32, 1024)

    gau_zero<<<(NB * NM) / 256, 256, 0, stream>>>(out);
    gau_main<<<NB * NCHUNK, TPB, 0, stream>>>(inputs, stars, out);
}

// Round 2
// 28.304 us; speedup vs baseline: 1.1643x; 1.1643x over previous
//
#include <hip/hip_runtime.h>

// out[b, m] = sum_n exp(-0.5 * ||inputs[b,n] - stars[m]||^2)
// B=32, N=4096, M=1024, D=3, fp32 in/out.
//
// exp(-0.5*d2) = 2^(q + Sx*x + Sy*y + Sz*z + K), q = -C2*||x||^2 (per point,
// prehoisted as E = 2^q), K = -C2*||s||^2, S* = log2(e)*s.
// Points processed in PAIRS with v_pk_fma_f32 (packed f32: 2 FMA/instr):
// per 2 exps: 3 pk_fma (dot) + 2 v_exp_f32 + 1 pk_fma (acc).

typedef float f32x2 __attribute__((ext_vector_type(2)));

#define NB 32
#define NN 4096
#define NM 1024
#define NCHUNK 32               // blocks per batch along N
#define NPB (NN / NCHUNK)       // 128 points per block
#define NPAIR (NPB / 2)         // 64 packed pairs
#define TPB 256                 // threads per block (4 waves)
#define MPT (NM / TPB)          // 4 stars per thread

__device__ __forceinline__ float exp2_hw(float x) {
#if __has_builtin(__builtin_amdgcn_exp2f)
    return __builtin_amdgcn_exp2f(x);
#else
    float r;
    asm("v_exp_f32 %0, %1" : "=v"(r) : "v"(x));
    return r;
#endif
}

__device__ __forceinline__ f32x2 pk_fma(f32x2 a, f32x2 b, f32x2 c) {
    f32x2 d;
    asm("v_pk_fma_f32 %0, %1, %2, %3" : "=v"(d) : "v"(a), "v"(b), "v"(c));
    return d;
}

__global__ __launch_bounds__(256) void gau_zero(float* __restrict__ out) {
    out[blockIdx.x * 256 + threadIdx.x] = 0.0f;
}

__global__ __launch_bounds__(TPB, 4) void gau_main(const float* __restrict__ inputs,
                                                   const float* __restrict__ stars,
                                                   float* __restrict__ out) {
    constexpr float C2  = 0.72134752044448169f;  // 0.5*log2(e)
    constexpr float L2E = 1.44269504088896340f;  // log2(e)

    const int b     = blockIdx.x / NCHUNK;
    const int chunk = blockIdx.x % NCHUNK;
    const int t     = threadIdx.x;

    // Pair-packed point tiles: XY[i] = (x0,x1,y0,y1), ZE[i] = (z0,z1,E0,E1)
    __shared__ float4 XY[NPAIR];
    __shared__ float4 ZE[NPAIR];

    if (t < NPAIR) {
        const float* p = inputs + ((size_t)b * NN + (size_t)chunk * NPB + 2 * (size_t)t) * 3;
        float x0 = p[0], y0 = p[1], z0 = p[2];
        float x1 = p[3], y1 = p[4], z1 = p[5];
        float q0 = -C2 * x0 * x0 - C2 * y0 * y0 - C2 * z0 * z0;
        float q1 = -C2 * x1 * x1 - C2 * y1 * y1 - C2 * z1 * z1;
        XY[t] = make_float4(x0, x1, y0, y1);
        ZE[t] = make_float4(z0, z1, exp2_hw(q0), exp2_hw(q1));
    }

    // Per-thread star constants (duplicated into both packed lanes)
    f32x2 Sx2[MPT], Sy2[MPT], Sz2[MPT], K2[MPT], acc[MPT];
#pragma unroll
    for (int k = 0; k < MPT; ++k) {
        int m = t + k * TPB;
        float sx = stars[3 * m + 0];
        float sy = stars[3 * m + 1];
        float sz = stars[3 * m + 2];
        float a = L2E * sx, c = L2E * sy, e = L2E * sz;
        float kk = -C2 * (sx * sx + sy * sy + sz * sz);
        Sx2[k] = f32x2{a, a};
        Sy2[k] = f32x2{c, c};
        Sz2[k] = f32x2{e, e};
        K2[k]  = f32x2{kk, kk};
        acc[k] = f32x2{0.0f, 0.0f};
    }

    __syncthreads();

#pragma unroll 2
    for (int i = 0; i < NPAIR; ++i) {
        float4 xy = XY[i];  // uniform address -> LDS broadcast
        float4 ze = ZE[i];
        f32x2 x2 = f32x2{xy.x, xy.y};
        f32x2 y2 = f32x2{xy.z, xy.w};
        f32x2 z2 = f32x2{ze.x, ze.y};
        f32x2 E2 = f32x2{ze.z, ze.w};
#pragma unroll
        for (int k = 0; k < MPT; ++k) {
            f32x2 inner = pk_fma(Sx2[k], x2, pk_fma(Sy2[k], y2, pk_fma(Sz2[k], z2, K2[k])));
            f32x2 e2 = f32x2{exp2_hw(inner.x), exp2_hw(inner.y)};
            acc[k] = pk_fma(E2, e2, acc[k]);
        }
    }

    float* ob = out + (size_t)b * NM;
#pragma unroll
    for (int k = 0; k < MPT; ++k) {
        atomicAdd(ob + t + k * TPB, acc[k].x + acc[k].y);
    }
}

extern "C" void kernel_launch(void* const* d_in, const int* in_sizes, int n_in,
                              void* d_out, int out_size, void* d_ws, size_t ws_size,
                              hipStream_t stream) {
    const float* inputs = (const float*)d_in[0];  // (32, 4096, 3)
    const float* stars  = (const float*)d_in[1];  // (1024, 3)
    float* out = (float*)d_out;                   // (32, 1024)

    gau_zero<<<(NB * NM) / 256, 256, 0, stream>>>(out);
    gau_main<<<NB * NCHUNK, TPB, 0, stream>>>(inputs, stars, out);
}